// Round 6
// baseline (34.260 us; speedup 1.0000x reference)
//
#include <hip/hip_runtime.h>
#include <math.h>

#define NSZ 512
#define MSZ 256
#define NPIX (6 * NSZ * NSZ)                      // 1,572,864 vertices
#define NQu  261121u                              // (NSZ-1)^2 quads per face
#define NQ2u 522242u                              // 2*NQu tris per face
#define NFACE 3133452                             // 6*2*NQu
#define F3TOT 9400356                             // NFACE*3 floats
#define NFT4  2350089                             // F3TOT/4 (one float4 per thread)
#define TS 32                                     // output tile
#define HS 34                                     // vert halo
#define QS 33                                     // quad halo
#define NVB 1536                                  // 6*16*16 vert blocks
#define NFB 9216                                  // faces block slots (>= ceil(NFT4/256))
#define GRID (NVB * 7)                            // [vert, f,f,f,f,f,f] groups

// ---- fast math helpers (raw HW op + 1 Newton step) -----------------------
__device__ inline float fast_rcp(float x) {
    float r = __builtin_amdgcn_rcpf(x);
    return r * (2.0f - x * r);
}
__device__ inline float fast_rsqrt(float d) {
    float r = __builtin_amdgcn_rsqf(d);
    return r * (1.5f - 0.5f * d * r * r);
}
__device__ inline float fast_sigmoid(float x) {
    float e = __builtin_amdgcn_exp2f(-1.442695040888963f * x);
    return fast_rcp(1.0f + e);
}
__device__ inline float lerpf(float a, float b, float w) {
    return __builtin_fmaf(w, b - a, a);
}

__global__ __launch_bounds__(256) void k_all(const float* __restrict__ vrt,
                                             const float* __restrict__ nrm,
                                             const float* __restrict__ ps,
                                             float* __restrict__ out0,
                                             float* __restrict__ out1,
                                             float* __restrict__ out2) {
    __shared__ float4 sv4[HS * HS];          // 18,496 B displaced verts (halo)
    __shared__ float4 tnA[QS * QS];          // 17,424 B tri0 unit normals
    __shared__ float4 tnB[QS * QS];          // 17,424 B tri1 unit normals

    int blk = blockIdx.x;
    int grp = blk / 7;
    int pos = blk - grp * 7;

    if (pos != 0) {
        // ========== faces path: 4 consecutive floats (<= 2 tris) / thread ====
        int t = (grp * 6 + (pos - 1)) * 256 + threadIdx.x;
        if (t >= NFT4) return;
        unsigned j   = 4u * (unsigned)t;
        unsigned tri = j / 3u;               // magic-mul
        unsigned c0  = j - tri * 3u;
        unsigned s   = tri / NQ2u;
        unsigned r1  = tri - s * NQ2u;
        unsigned ty  = (r1 >= NQu) ? 1u : 0u;
        unsigned qi  = r1 - ty * NQu;
        unsigned R   = qi / 511u;
        unsigned Q   = qi - R * 511u;
        unsigned a0  = (s << 18) + (R << 9) + Q;
        // advance one triangle (rare carries, branchless-ish)
        unsigned Qn = Q + 1u, Rn = R, tyn = ty, sn = s;
        if (Qn == 511u) {
            Qn = 0u; Rn += 1u;
            if (Rn == 511u) { Rn = 0u; tyn ^= 1u; if (tyn == 0u) sn += 1u; }
        }
        unsigned a1 = (sn << 18) + (Rn << 9) + Qn;

        float v[4];
#pragma unroll
        for (int i = 0; i < 4; ++i) {
            unsigned ci = c0 + (unsigned)i;
            unsigned nx = (ci >= 3u) ? 1u : 0u;
            ci -= nx * 3u;
            unsigned a  = nx ? a1 : a0;
            unsigned tt = nx ? tyn : ty;
            // ty=0: [+0,+1,+512]   ty=1: [+1,+513,+512]
            unsigned sel = (ci == 2u) ? 512u : ((ci == 1u) ? (tt ? 513u : 1u) : tt);
            v[i] = (float)(a + sel);
        }
        ((float4*)out1)[t] = make_float4(v[0], v[1], v[2], v[3]);
        return;
    }

    // ========== vert + normals path ==========
    int f   = grp >> 8;
    int tl  = grp & 255;
    int tr  = (tl >> 4) * TS;
    int tq  = (tl & 15) * TS;
    int fbm = f * (MSZ * MSZ);
    int fbn = f * (NSZ * NSZ);

    // phase 1: 34x34 halo of displaced verts -> sv4 (+ write interior to out0)
    const float scale = 255.0f / 511.0f;
    for (int p = threadIdx.x; p < HS * HS; p += 256) {
        int pr = p / HS, pq = p - pr * HS;
        int y = tr + pr - 1, x = tq + pq - 1;
        int yc = min(max(y, 0), NSZ - 1);
        int xc = min(max(x, 0), NSZ - 1);

        float cy = (float)yc * scale;           // in [0, ~255.0]
        float cx = (float)xc * scale;
        int iy0 = min((int)cy, MSZ - 1);
        int ix0 = min((int)cx, MSZ - 1);
        float wy = cy - (float)iy0;
        float wx = cx - (float)ix0;
        // contiguous-pair base with edge-exact weight remap:
        // interior: (iya=iy0, wya=wy); edge iy0==255: pair (254,255), wya=1 -> exact v255
        int   iya = min(iy0, MSZ - 2);
        int   ixa = min(ix0, MSZ - 2);
        float wya = (iy0 < MSZ - 1) ? wy : 1.0f;
        float wxa = (ix0 < MSZ - 1) ? wx : 1.0f;

        int g0 = (fbm + iya * MSZ + ixa) * 3;        // row iya: 6 contiguous floats
        int g1 = g0 + MSZ * 3;                        // row iya+1

        // vrt bilinear (compiler merges these into dwordx4/x2 loads)
        float va0 = vrt[g0], va1 = vrt[g0+1], va2 = vrt[g0+2];
        float va3 = vrt[g0+3], va4 = vrt[g0+4], va5 = vrt[g0+5];
        float vb0 = vrt[g1], vb1 = vrt[g1+1], vb2 = vrt[g1+2];
        float vb3 = vrt[g1+3], vb4 = vrt[g1+4], vb5 = vrt[g1+5];
        float na0 = nrm[g0], na1 = nrm[g0+1], na2 = nrm[g0+2];
        float na3 = nrm[g0+3], na4 = nrm[g0+4], na5 = nrm[g0+5];
        float nb0 = nrm[g1], nb1 = nrm[g1+1], nb2 = nrm[g1+2];
        float nb3 = nrm[g1+3], nb4 = nrm[g1+4], nb5 = nrm[g1+5];

        float vx = lerpf(lerpf(va0, va3, wxa), lerpf(vb0, vb3, wxa), wya);
        float vy = lerpf(lerpf(va1, va4, wxa), lerpf(vb1, vb4, wxa), wya);
        float vz = lerpf(lerpf(va2, va5, wxa), lerpf(vb2, vb5, wxa), wya);
        float nx = lerpf(lerpf(na0, na3, wxa), lerpf(nb0, nb3, wxa), wya);
        float ny = lerpf(lerpf(na1, na4, wxa), lerpf(nb1, nb4, wxa), wya);
        float nz = lerpf(lerpf(na2, na5, wxa), lerpf(nb2, nb5, wxa), wya);

        float mag = __builtin_amdgcn_sqrtf(nx * nx + ny * ny + nz * nz);
        float sig = fast_sigmoid(ps[fbn + yc * NSZ + xc]);
        float add = 0.5f * sig * mag;
        float ox = vx + add, oy = vy + add, oz = vz + add;

        sv4[p] = make_float4(ox, oy, oz, 0.0f);
        if (pr >= 1 && pr <= TS && pq >= 1 && pq <= TS) {
            int gi = (fbn + y * NSZ + x) * 3;
            out0[gi + 0] = ox;
            out0[gi + 1] = oy;
            out0[gi + 2] = oz;
        }
    }
    __syncthreads();

    // phase 1.5: unit normals of the 33x33 quad-halo's 2 tris each, ONCE.
    // Out-of-face quads are exactly degenerate (clamped halo duplicates a
    // corner pair) -> cross = 0 exactly -> fmax clamp keeps rsq finite -> 0.
    for (int p = threadIdx.x; p < QS * QS; p += 256) {
        int Ri = p / QS, Qi = p - Ri * QS;
        int base = Ri * HS + Qi;
        float4 A = sv4[base];
        float4 B = sv4[base + 1];
        float4 C = sv4[base + HS];
        float4 D = sv4[base + HS + 1];

        {   // tri0: (A, B, C)
            float e1x = B.x - A.x, e1y = B.y - A.y, e1z = B.z - A.z;
            float e2x = C.x - A.x, e2y = C.y - A.y, e2z = C.z - A.z;
            float cxp = e1y * e2z - e1z * e2y;
            float cyp = e1z * e2x - e1x * e2z;
            float czp = e1x * e2y - e1y * e2x;
            float d = fmaxf(cxp * cxp + cyp * cyp + czp * czp, 1e-24f);
            float r = fast_rsqrt(d);
            tnA[p] = make_float4(cxp * r, cyp * r, czp * r, 0.0f);
        }
        {   // tri1: (B, D, C)
            float e1x = D.x - B.x, e1y = D.y - B.y, e1z = D.z - B.z;
            float e2x = C.x - B.x, e2y = C.y - B.y, e2z = C.z - B.z;
            float cxp = e1y * e2z - e1z * e2y;
            float cyp = e1z * e2x - e1x * e2z;
            float czp = e1x * e2y - e1y * e2x;
            float d = fmaxf(cxp * cxp + cyp * cyp + czp * czp, 1e-24f);
            float r = fast_rsqrt(d);
            tnB[p] = make_float4(cxp * r, cyp * r, czp * r, 0.0f);
        }
    }
    __syncthreads();

    // phase 2: vertex normal = normalize( sum of 6 adjacent tri normals )
    float sg = (f == 1 || f == 2 || f == 5) ? 1.0f : -1.0f;
    for (int p = threadIdx.x; p < TS * TS; p += 256) {
        int r = p >> 5, q = p & 31;
        int q00 = r * QS + q;
        int q01 = q00 + 1;
        int q10 = q00 + QS;
        int q11 = q10 + 1;

        float4 t0 = tnA[q11];
        float4 t1 = tnA[q10];
        float4 t2 = tnA[q01];
        float4 t3 = tnB[q10];
        float4 t4 = tnB[q00];
        float4 t5 = tnB[q01];

        float ax = t0.x + t1.x + t2.x + t3.x + t4.x + t5.x;
        float ay = t0.y + t1.y + t2.y + t3.y + t4.y + t5.y;
        float az = t0.z + t1.z + t2.z + t3.z + t4.z + t5.z;

        float d  = fmaxf(ax * ax + ay * ay + az * az, 1e-24f);
        float rs = fast_rsqrt(d) * sg;
        int gi = (fbn + (tr + r) * NSZ + (tq + q)) * 3;
        out2[gi + 0] = ax * rs;
        out2[gi + 1] = ay * rs;
        out2[gi + 2] = az * rs;
    }
}

extern "C" void kernel_launch(void* const* d_in, const int* in_sizes, int n_in,
                              void* d_out, int out_size, void* d_ws, size_t ws_size,
                              hipStream_t stream) {
    const float* vrt = (const float*)d_in[0];
    const float* nrm = (const float*)d_in[1];
    const float* ps  = (const float*)d_in[2];

    float* out0 = (float*)d_out;                 // vert:    6*512*512*3
    float* out1 = out0 + (size_t)NPIX * 3;       // faces:   NFACE*3
    float* out2 = out1 + (size_t)F3TOT;          // normals: 6*512*512*3

    k_all<<<GRID, 256, 0, stream>>>(vrt, nrm, ps, out0, out1, out2);
}

// Round 7
// 32.204 us; speedup vs baseline: 1.0639x; 1.0639x over previous
//
#include <hip/hip_runtime.h>
#include <math.h>

#define NSZ 512
#define MSZ 256
#define NPIX (6 * NSZ * NSZ)                      // 1,572,864 vertices
#define NQu  261121u                              // (NSZ-1)^2 quads per face
#define NQ2u 522242u                              // 2*NQu tris per face
#define NFACE 3133452                             // 6*2*NQu
#define F3TOT 9400356                             // NFACE*3 floats
#define NFT4  2350089                             // F3TOT/4 (one float4 per thread)
#define TS 32                                     // output tile
#define HS 34                                     // vert halo
#define NVB 1536                                  // 6*16*16 vert blocks
#define GRID (NVB * 7)                            // [vert, f,f,f,f,f,f] groups

// ---- fast math helpers (raw HW op + 1 Newton step) -----------------------
__device__ inline float fast_rcp(float x) {
    float r = __builtin_amdgcn_rcpf(x);
    return r * (2.0f - x * r);
}
__device__ inline float fast_rsqrt(float d) {
    float r = __builtin_amdgcn_rsqf(d);
    return r * (1.5f - 0.5f * d * r * r);
}
__device__ inline float fast_sigmoid(float x) {
    float e = __builtin_amdgcn_exp2f(-1.442695040888963f * x);
    return fast_rcp(1.0f + e);
}
__device__ inline float lerpf(float a, float b, float w) {
    return __builtin_fmaf(w, b - a, a);
}

struct F3 { float x, y, z; };

// triangle unit-normal accumulate; degenerate tris (two identical corners,
// from clamped halo rows/cols) give an exactly-zero cross -> contribute 0.
__device__ inline void tri_acc(const F3 A, const F3 B, const F3 C,
                               float& ax, float& ay, float& az) {
    float e1x = B.x - A.x, e1y = B.y - A.y, e1z = B.z - A.z;
    float e2x = C.x - A.x, e2y = C.y - A.y, e2z = C.z - A.z;
    float nx = e1y * e2z - e1z * e2y;
    float ny = e1z * e2x - e1x * e2z;
    float nz = e1x * e2y - e1y * e2x;
    float d  = fmaxf(nx * nx + ny * ny + nz * nz, 1e-24f);
    float r  = fast_rsqrt(d);
    ax += nx * r; ay += ny * r; az += nz * r;
}

__global__ __launch_bounds__(256, 6) void k_all(const float* __restrict__ vrt,
                                                const float* __restrict__ nrm,
                                                const float* __restrict__ ps,
                                                float* __restrict__ out0,
                                                float* __restrict__ out1,
                                                float* __restrict__ out2) {
    __shared__ float sv[HS * HS * 3];        // 13,872 B — the ONLY LDS

    int blk = blockIdx.x;
    int grp = blk / 7;
    int pos = blk - grp * 7;

    if (pos != 0) {
        // ========== faces path: 4 consecutive floats (<= 2 tris) / thread ====
        int t = (grp * 6 + (pos - 1)) * 256 + threadIdx.x;
        if (t >= NFT4) return;
        unsigned j   = 4u * (unsigned)t;
        unsigned tri = j / 3u;               // magic-mul
        unsigned c0  = j - tri * 3u;
        unsigned s   = tri / NQ2u;
        unsigned r1  = tri - s * NQ2u;
        unsigned ty  = (r1 >= NQu) ? 1u : 0u;
        unsigned qi  = r1 - ty * NQu;
        unsigned R   = qi / 511u;
        unsigned Q   = qi - R * 511u;
        unsigned a0  = (s << 18) + (R << 9) + Q;
        // advance one triangle (rare carries)
        unsigned Qn = Q + 1u, Rn = R, tyn = ty, sn = s;
        if (Qn == 511u) {
            Qn = 0u; Rn += 1u;
            if (Rn == 511u) { Rn = 0u; tyn ^= 1u; if (tyn == 0u) sn += 1u; }
        }
        unsigned a1 = (sn << 18) + (Rn << 9) + Qn;

        float v[4];
#pragma unroll
        for (int i = 0; i < 4; ++i) {
            unsigned ci = c0 + (unsigned)i;
            unsigned nx = (ci >= 3u) ? 1u : 0u;
            ci -= nx * 3u;
            unsigned a  = nx ? a1 : a0;
            unsigned tt = nx ? tyn : ty;
            // ty=0: [+0,+1,+512]   ty=1: [+1,+513,+512]
            unsigned sel = (ci == 2u) ? 512u : ((ci == 1u) ? (tt ? 513u : 1u) : tt);
            v[i] = (float)(a + sel);
        }
        ((float4*)out1)[t] = make_float4(v[0], v[1], v[2], v[3]);
        return;
    }

    // ========== vert + normals path ==========
    int f   = grp >> 8;
    int tl  = grp & 255;
    int tr  = (tl >> 4) * TS;
    int tq  = (tl & 15) * TS;
    int fbm = f * (MSZ * MSZ);
    int fbn = f * (NSZ * NSZ);

    // phase 1: 34x34 halo of displaced verts -> sv (+ write interior to out0)
    const float scale = 255.0f / 511.0f;
    for (int p = threadIdx.x; p < HS * HS; p += 256) {
        int pr = p / HS, pq = p - pr * HS;
        int y = tr + pr - 1, x = tq + pq - 1;
        int yc = min(max(y, 0), NSZ - 1);
        int xc = min(max(x, 0), NSZ - 1);

        float cy = (float)yc * scale;
        float cx = (float)xc * scale;
        int iy0 = min((int)cy, MSZ - 1);
        int ix0 = min((int)cx, MSZ - 1);
        float wy = cy - (float)iy0;
        float wx = cx - (float)ix0;
        // contiguous-pair base with edge-exact weight remap
        int   iya = min(iy0, MSZ - 2);
        int   ixa = min(ix0, MSZ - 2);
        float wya = (iy0 < MSZ - 1) ? wy : 1.0f;
        float wxa = (ix0 < MSZ - 1) ? wx : 1.0f;

        int g0 = (fbm + iya * MSZ + ixa) * 3;        // row iya: 6 contiguous floats
        int g1 = g0 + MSZ * 3;                        // row iya+1

        float va0 = vrt[g0], va1 = vrt[g0+1], va2 = vrt[g0+2];
        float va3 = vrt[g0+3], va4 = vrt[g0+4], va5 = vrt[g0+5];
        float vb0 = vrt[g1], vb1 = vrt[g1+1], vb2 = vrt[g1+2];
        float vb3 = vrt[g1+3], vb4 = vrt[g1+4], vb5 = vrt[g1+5];
        float vx = lerpf(lerpf(va0, va3, wxa), lerpf(vb0, vb3, wxa), wya);
        float vy = lerpf(lerpf(va1, va4, wxa), lerpf(vb1, vb4, wxa), wya);
        float vz = lerpf(lerpf(va2, va5, wxa), lerpf(vb2, vb5, wxa), wya);

        float na0 = nrm[g0], na1 = nrm[g0+1], na2 = nrm[g0+2];
        float na3 = nrm[g0+3], na4 = nrm[g0+4], na5 = nrm[g0+5];
        float nb0 = nrm[g1], nb1 = nrm[g1+1], nb2 = nrm[g1+2];
        float nb3 = nrm[g1+3], nb4 = nrm[g1+4], nb5 = nrm[g1+5];
        float nx = lerpf(lerpf(na0, na3, wxa), lerpf(nb0, nb3, wxa), wya);
        float ny = lerpf(lerpf(na1, na4, wxa), lerpf(nb1, nb4, wxa), wya);
        float nz = lerpf(lerpf(na2, na5, wxa), lerpf(nb2, nb5, wxa), wya);

        float mag = __builtin_amdgcn_sqrtf(nx * nx + ny * ny + nz * nz);
        float sig = fast_sigmoid(ps[fbn + yc * NSZ + xc]);
        float add = 0.5f * sig * mag;
        float ox = vx + add, oy = vy + add, oz = vz + add;

        sv[p * 3 + 0] = ox;
        sv[p * 3 + 1] = oy;
        sv[p * 3 + 2] = oz;
        if (pr >= 1 && pr <= TS && pq >= 1 && pq <= TS) {
            int gi = (fbn + y * NSZ + x) * 3;
            out0[gi + 0] = ox;
            out0[gi + 1] = oy;
            out0[gi + 2] = oz;
        }
    }
    __syncthreads();

    // phase 2: vertex normal = normalize( sum of 6 adjacent tri normals ),
    // recomputed per vertex straight from sv (stride-3 scalar LDS reads,
    // gcd(3,32)=1 -> conflict-free).
    float sg = (f == 1 || f == 2 || f == 5) ? 1.0f : -1.0f;
    for (int p = threadIdx.x; p < TS * TS; p += 256) {
        int r = p >> 5, q = p & 31;
        int lc = ((r + 1) * HS + (q + 1)) * 3;

        #define LD(off) { sv[(off)], sv[(off) + 1], sv[(off) + 2] }
        F3 C  = LD(lc);
        F3 W  = LD(lc - 3);
        F3 E  = LD(lc + 3);
        F3 Nn = LD(lc - HS * 3);
        F3 S  = LD(lc + HS * 3);
        F3 NE = LD(lc - HS * 3 + 3);
        F3 SW = LD(lc + HS * 3 - 3);
        #undef LD

        float ax = 0.0f, ay = 0.0f, az = 0.0f;
        // tri0 of quads (r,q), (r,q-1), (r-1,q)
        tri_acc(C,  E,  S,  ax, ay, az);
        tri_acc(W,  C,  SW, ax, ay, az);
        tri_acc(Nn, NE, C,  ax, ay, az);
        // tri1 of quads (r,q-1), (r-1,q-1), (r-1,q)
        tri_acc(C,  S,  SW, ax, ay, az);
        tri_acc(Nn, C,  W,  ax, ay, az);
        tri_acc(NE, E,  C,  ax, ay, az);

        float d  = fmaxf(ax * ax + ay * ay + az * az, 1e-24f);
        float rs = fast_rsqrt(d) * sg;
        int gi = (fbn + (tr + r) * NSZ + (tq + q)) * 3;
        out2[gi + 0] = ax * rs;
        out2[gi + 1] = ay * rs;
        out2[gi + 2] = az * rs;
    }
}

extern "C" void kernel_launch(void* const* d_in, const int* in_sizes, int n_in,
                              void* d_out, int out_size, void* d_ws, size_t ws_size,
                              hipStream_t stream) {
    const float* vrt = (const float*)d_in[0];
    const float* nrm = (const float*)d_in[1];
    const float* ps  = (const float*)d_in[2];

    float* out0 = (float*)d_out;                 // vert:    6*512*512*3
    float* out1 = out0 + (size_t)NPIX * 3;       // faces:   NFACE*3
    float* out2 = out1 + (size_t)F3TOT;          // normals: 6*512*512*3

    k_all<<<GRID, 256, 0, stream>>>(vrt, nrm, ps, out0, out1, out2);
}

// Round 8
// 28.491 us; speedup vs baseline: 1.2025x; 1.1303x over previous
//
#include <hip/hip_runtime.h>
#include <math.h>

#define NSZ 512
#define MSZ 256
#define NPIX (6 * NSZ * NSZ)                      // 1,572,864 vertices
#define NQu  261121u                              // (NSZ-1)^2 quads per face
#define NQ2u 522242u                              // 2*NQu tris per face
#define NFACE 3133452                             // 6*2*NQu
#define F3TOT 9400356                             // NFACE*3 floats
#define NFT4  2350089                             // F3TOT/4 (one float4 per thread)
#define TS 32                                     // output tile
#define HS 34                                     // vert halo
#define QS 33                                     // quad halo
#define NVB 1536                                  // 6*16*16 vert blocks
#define NFB ((NFT4 + 255) / 256)                  // 9181 faces blocks
#define GRID (NVB + NFB)

// ---- fast math helpers (raw HW op + 1 Newton step) -----------------------
__device__ inline float fast_rcp(float x) {
    float r = __builtin_amdgcn_rcpf(x);
    return r * (2.0f - x * r);
}
__device__ inline float fast_rsqrt(float d) {
    float r = __builtin_amdgcn_rsqf(d);
    return r * (1.5f - 0.5f * d * r * r);
}
__device__ inline float fast_sigmoid(float x) {
    float e = __builtin_amdgcn_exp2f(-1.442695040888963f * x);
    return fast_rcp(1.0f + e);
}
__device__ inline float lerpf(float a, float b, float w) {
    return __builtin_fmaf(w, b - a, a);
}

__global__ __launch_bounds__(256) void k_all(const float* __restrict__ vrt,
                                             const float* __restrict__ nrm,
                                             const float* __restrict__ ps,
                                             float* __restrict__ out0,
                                             float* __restrict__ out1,
                                             float* __restrict__ out2) {
    // scalar-float LDS, stride-3 accesses: gcd(3,32)=1 -> bank-conflict-free.
    // total 40,008 B -> 4 blocks/CU.
    __shared__ float sv [HS * HS * 3];       // 13,872 B displaced verts (halo)
    __shared__ float tn0[QS * QS * 3];       // 13,068 B tri0 unit normals
    __shared__ float tn1[QS * QS * 3];       // 13,068 B tri1 unit normals

    int blk = blockIdx.x;

    if (blk >= NVB) {
        // ========== faces path: 4 consecutive floats (<= 2 tris) / thread ====
        int t = (blk - NVB) * 256 + threadIdx.x;
        if (t >= NFT4) return;
        unsigned j   = 4u * (unsigned)t;
        unsigned tri = j / 3u;               // magic-mul
        unsigned c0  = j - tri * 3u;
        unsigned s   = tri / NQ2u;
        unsigned r1  = tri - s * NQ2u;
        unsigned ty  = (r1 >= NQu) ? 1u : 0u;
        unsigned qi  = r1 - ty * NQu;
        unsigned R   = qi / 511u;
        unsigned Q   = qi - R * 511u;
        unsigned a0  = (s << 18) + (R << 9) + Q;
        // advance one triangle (rare carries)
        unsigned Qn = Q + 1u, Rn = R, tyn = ty, sn = s;
        if (Qn == 511u) {
            Qn = 0u; Rn += 1u;
            if (Rn == 511u) { Rn = 0u; tyn ^= 1u; if (tyn == 0u) sn += 1u; }
        }
        unsigned a1 = (sn << 18) + (Rn << 9) + Qn;

        float v[4];
#pragma unroll
        for (int i = 0; i < 4; ++i) {
            unsigned ci = c0 + (unsigned)i;
            unsigned nx = (ci >= 3u) ? 1u : 0u;
            ci -= nx * 3u;
            unsigned a  = nx ? a1 : a0;
            unsigned tt = nx ? tyn : ty;
            // ty=0: [+0,+1,+512]   ty=1: [+1,+513,+512]
            unsigned sel = (ci == 2u) ? 512u : ((ci == 1u) ? (tt ? 513u : 1u) : tt);
            v[i] = (float)(a + sel);
        }
        ((float4*)out1)[t] = make_float4(v[0], v[1], v[2], v[3]);
        return;
    }

    // ========== vert + normals path ==========
    int f   = blk >> 8;
    int tl  = blk & 255;
    int tr  = (tl >> 4) * TS;
    int tq  = (tl & 15) * TS;
    int fbm = f * (MSZ * MSZ);
    int fbn = f * (NSZ * NSZ);

    // phase 1: 34x34 halo of displaced verts -> sv (+ write interior to out0)
    const float scale = 255.0f / 511.0f;
    for (int p = threadIdx.x; p < HS * HS; p += 256) {
        int pr = p / HS, pq = p - pr * HS;
        int y = tr + pr - 1, x = tq + pq - 1;
        int yc = min(max(y, 0), NSZ - 1);
        int xc = min(max(x, 0), NSZ - 1);

        float cy = (float)yc * scale;
        float cx = (float)xc * scale;
        int iy0 = min((int)cy, MSZ - 1);
        int ix0 = min((int)cx, MSZ - 1);
        float wy = cy - (float)iy0;
        float wx = cx - (float)ix0;
        // contiguous-pair base with edge-exact weight remap
        int   iya = min(iy0, MSZ - 2);
        int   ixa = min(ix0, MSZ - 2);
        float wya = (iy0 < MSZ - 1) ? wy : 1.0f;
        float wxa = (ix0 < MSZ - 1) ? wx : 1.0f;

        int g0 = (fbm + iya * MSZ + ixa) * 3;        // row iya: 6 contiguous floats
        int g1 = g0 + MSZ * 3;                        // row iya+1

        float va0 = vrt[g0], va1 = vrt[g0+1], va2 = vrt[g0+2];
        float va3 = vrt[g0+3], va4 = vrt[g0+4], va5 = vrt[g0+5];
        float vb0 = vrt[g1], vb1 = vrt[g1+1], vb2 = vrt[g1+2];
        float vb3 = vrt[g1+3], vb4 = vrt[g1+4], vb5 = vrt[g1+5];
        float vx = lerpf(lerpf(va0, va3, wxa), lerpf(vb0, vb3, wxa), wya);
        float vy = lerpf(lerpf(va1, va4, wxa), lerpf(vb1, vb4, wxa), wya);
        float vz = lerpf(lerpf(va2, va5, wxa), lerpf(vb2, vb5, wxa), wya);

        float na0 = nrm[g0], na1 = nrm[g0+1], na2 = nrm[g0+2];
        float na3 = nrm[g0+3], na4 = nrm[g0+4], na5 = nrm[g0+5];
        float nb0 = nrm[g1], nb1 = nrm[g1+1], nb2 = nrm[g1+2];
        float nb3 = nrm[g1+3], nb4 = nrm[g1+4], nb5 = nrm[g1+5];
        float nx = lerpf(lerpf(na0, na3, wxa), lerpf(nb0, nb3, wxa), wya);
        float ny = lerpf(lerpf(na1, na4, wxa), lerpf(nb1, nb4, wxa), wya);
        float nz = lerpf(lerpf(na2, na5, wxa), lerpf(nb2, nb5, wxa), wya);

        float mag = __builtin_amdgcn_sqrtf(nx * nx + ny * ny + nz * nz);
        float sig = fast_sigmoid(ps[fbn + yc * NSZ + xc]);
        float add = 0.5f * sig * mag;
        float ox = vx + add, oy = vy + add, oz = vz + add;

        sv[p * 3 + 0] = ox;
        sv[p * 3 + 1] = oy;
        sv[p * 3 + 2] = oz;
        if (pr >= 1 && pr <= TS && pq >= 1 && pq <= TS) {
            int gi = (fbn + y * NSZ + x) * 3;
            out0[gi + 0] = ox;
            out0[gi + 1] = oy;
            out0[gi + 2] = oz;
        }
    }
    __syncthreads();

    // phase 1.5: unit normals of the 33x33 quad-halo's 2 tris each, ONCE.
    // Out-of-face quads are exactly degenerate (clamped halo duplicates a
    // corner) -> cross = 0 exactly -> contributes 0. No masking needed.
    for (int p = threadIdx.x; p < QS * QS; p += 256) {
        int Ri = p / QS, Qi = p - Ri * QS;
        int base = (Ri * HS + Qi) * 3;
        float Axx = sv[base + 0],          Axy = sv[base + 1],          Axz = sv[base + 2];
        float Bxx = sv[base + 3],          Bxy = sv[base + 4],          Bxz = sv[base + 5];
        float Cxx = sv[base + HS*3 + 0],   Cxy = sv[base + HS*3 + 1],   Cxz = sv[base + HS*3 + 2];
        float Dxx = sv[base + HS*3 + 3],   Dxy = sv[base + HS*3 + 4],   Dxz = sv[base + HS*3 + 5];

        {   // tri0: (A, B, C)
            float e1x = Bxx - Axx, e1y = Bxy - Axy, e1z = Bxz - Axz;
            float e2x = Cxx - Axx, e2y = Cxy - Axy, e2z = Cxz - Axz;
            float nx = e1y * e2z - e1z * e2y;
            float ny = e1z * e2x - e1x * e2z;
            float nz = e1x * e2y - e1y * e2x;
            float d  = fmaxf(nx * nx + ny * ny + nz * nz, 1e-24f);
            float r  = fast_rsqrt(d);
            tn0[p * 3 + 0] = nx * r;
            tn0[p * 3 + 1] = ny * r;
            tn0[p * 3 + 2] = nz * r;
        }
        {   // tri1: (B, D, C)
            float e1x = Dxx - Bxx, e1y = Dxy - Bxy, e1z = Dxz - Bxz;
            float e2x = Cxx - Bxx, e2y = Cxy - Bxy, e2z = Cxz - Bxz;
            float nx = e1y * e2z - e1z * e2y;
            float ny = e1z * e2x - e1x * e2z;
            float nz = e1x * e2y - e1y * e2x;
            float d  = fmaxf(nx * nx + ny * ny + nz * nz, 1e-24f);
            float r  = fast_rsqrt(d);
            tn1[p * 3 + 0] = nx * r;
            tn1[p * 3 + 1] = ny * r;
            tn1[p * 3 + 2] = nz * r;
        }
    }
    __syncthreads();

    // phase 2: vertex normal = normalize( sum of 6 adjacent tri normals )
    float sg = (f == 1 || f == 2 || f == 5) ? 1.0f : -1.0f;
    for (int p = threadIdx.x; p < TS * TS; p += 256) {
        int r = p >> 5, q = p & 31;
        int q00 = (r * QS + q) * 3;
        int q01 = q00 + 3;
        int q10 = q00 + QS * 3;
        int q11 = q10 + 3;

        float ax = tn0[q11 + 0] + tn0[q10 + 0] + tn0[q01 + 0]
                 + tn1[q10 + 0] + tn1[q00 + 0] + tn1[q01 + 0];
        float ay = tn0[q11 + 1] + tn0[q10 + 1] + tn0[q01 + 1]
                 + tn1[q10 + 1] + tn1[q00 + 1] + tn1[q01 + 1];
        float az = tn0[q11 + 2] + tn0[q10 + 2] + tn0[q01 + 2]
                 + tn1[q10 + 2] + tn1[q00 + 2] + tn1[q01 + 2];

        float d  = fmaxf(ax * ax + ay * ay + az * az, 1e-24f);
        float rs = fast_rsqrt(d) * sg;
        int gi = (fbn + (tr + r) * NSZ + (tq + q)) * 3;
        out2[gi + 0] = ax * rs;
        out2[gi + 1] = ay * rs;
        out2[gi + 2] = az * rs;
    }
}

extern "C" void kernel_launch(void* const* d_in, const int* in_sizes, int n_in,
                              void* d_out, int out_size, void* d_ws, size_t ws_size,
                              hipStream_t stream) {
    const float* vrt = (const float*)d_in[0];
    const float* nrm = (const float*)d_in[1];
    const float* ps  = (const float*)d_in[2];

    float* out0 = (float*)d_out;                 // vert:    6*512*512*3
    float* out1 = out0 + (size_t)NPIX * 3;       // faces:   NFACE*3
    float* out2 = out1 + (size_t)F3TOT;          // normals: 6*512*512*3

    k_all<<<GRID, 256, 0, stream>>>(vrt, nrm, ps, out0, out1, out2);
}

// Round 10
// 26.465 us; speedup vs baseline: 1.2945x; 1.0766x over previous
//
#include <hip/hip_runtime.h>
#include <math.h>

#define NSZ 512
#define MSZ 256
#define NPIX (6 * NSZ * NSZ)                      // 1,572,864 vertices
#define NQu  261121u                              // (NSZ-1)^2 quads per face
#define NQ2u 522242u                              // 2*NQu tris per face
#define NFACE 3133452                             // 6*2*NQu
#define F3TOT 9400356                             // NFACE*3 floats
#define NFT12 783363                              // F3TOT/12 (4 whole tris / thread)
#define TS 32                                     // output tile
#define HS 34                                     // vert halo
#define QS 33                                     // quad halo
#define NVB 1536                                  // 6*16*16 vert blocks
#define NFB ((NFT12 + 255) / 256)                 // 3061 faces blocks
#define GRID (NVB + NFB)

typedef __fp16 h2_t __attribute__((ext_vector_type(2)));

// ---- fast math helpers (raw HW op + 1 Newton step) -----------------------
__device__ inline float fast_rcp(float x) {
    float r = __builtin_amdgcn_rcpf(x);
    return r * (2.0f - x * r);
}
__device__ inline float fast_rsqrt(float d) {
    float r = __builtin_amdgcn_rsqf(d);
    return r * (1.5f - 0.5f * d * r * r);
}
__device__ inline float fast_sigmoid(float x) {
    float e = __builtin_amdgcn_exp2f(-1.442695040888963f * x);
    return fast_rcp(1.0f + e);
}
__device__ inline float lerpf(float a, float b, float w) {
    return __builtin_fmaf(w, b - a, a);
}
// pack two floats to half2 bits (one v_cvt_pkrtz_f16_f32)
__device__ inline unsigned pkh2(float x, float y) {
    h2_t h = __builtin_amdgcn_cvt_pkrtz(x, y);
    return __builtin_bit_cast(unsigned, h);
}
__device__ inline float2 uph2(unsigned u) {
    h2_t h = __builtin_bit_cast(h2_t, u);
    return make_float2((float)h.x, (float)h.y);
}

__global__ __launch_bounds__(256) void k_all(const float* __restrict__ vrt,
                                             const float* __restrict__ nrm,
                                             const float* __restrict__ ps,
                                             float* __restrict__ out0,
                                             float* __restrict__ out1,
                                             float* __restrict__ out2) {
    // LDS: 13,872 + 8,712 + 8,712 = 31,296 B -> 5 blocks/CU.
    __shared__ float sv [HS * HS * 3];       // displaced verts (halo), fp32
    __shared__ uint2 tn0p[QS * QS];          // tri0 unit normals, fp16-packed
    __shared__ uint2 tn1p[QS * QS];          // tri1 unit normals, fp16-packed

    int blk = blockIdx.x;

    if (blk >= NVB) {
        // ========== faces path: 12 floats = 4 whole tris / thread ==========
        int t = (blk - NVB) * 256 + threadIdx.x;
        if (t >= NFT12) return;
        unsigned tri = 4u * (unsigned)t;          // j = 12t -> tri = 4t, c0 = 0
        unsigned s   = tri / NQ2u;
        unsigned r1  = tri - s * NQ2u;
        unsigned ty  = (r1 >= NQu) ? 1u : 0u;
        unsigned qi  = r1 - ty * NQu;
        unsigned R   = qi / 511u;
        unsigned Q   = qi - R * 511u;

        unsigned a[4], tt[4];
        unsigned aq = Q, aR = R, aty = ty, as_ = s;
#pragma unroll
        for (int k = 0; k < 4; ++k) {
            a[k]  = (as_ << 18) + (aR << 9) + aq;
            tt[k] = aty;
            aq++;
            if (aq == 511u) {
                aq = 0u; aR++;
                if (aR == 511u) { aR = 0u; aty ^= 1u; if (aty == 0u) as_++; }
            }
        }
        // tri k: ty=0 -> (a, a+1, a+512); ty=1 -> (a+1, a+513, a+512)
        float w[12];
#pragma unroll
        for (int k = 0; k < 4; ++k) {
            w[3*k + 0] = (float)(a[k] + (tt[k] ? 1u : 0u));
            w[3*k + 1] = (float)(a[k] + (tt[k] ? 513u : 1u));
            w[3*k + 2] = (float)(a[k] + 512u);
        }
        float4* o = (float4*)out1 + 3 * t;        // 12t floats: 16B-aligned
        o[0] = make_float4(w[0], w[1], w[2],  w[3]);
        o[1] = make_float4(w[4], w[5], w[6],  w[7]);
        o[2] = make_float4(w[8], w[9], w[10], w[11]);
        return;
    }

    // ========== vert + normals path ==========
    int f   = blk >> 8;
    int tl  = blk & 255;
    int tr  = (tl >> 4) * TS;
    int tq  = (tl & 15) * TS;
    int fbm = f * (MSZ * MSZ);
    int fbn = f * (NSZ * NSZ);

    // phase 1: 34x34 halo of displaced verts -> sv (+ write interior to out0)
    const float scale = 255.0f / 511.0f;
    for (int p = threadIdx.x; p < HS * HS; p += 256) {
        int pr = p / HS, pq = p - pr * HS;
        int y = tr + pr - 1, x = tq + pq - 1;
        int yc = min(max(y, 0), NSZ - 1);
        int xc = min(max(x, 0), NSZ - 1);

        float cy = (float)yc * scale;
        float cx = (float)xc * scale;
        int iy0 = min((int)cy, MSZ - 1);
        int ix0 = min((int)cx, MSZ - 1);
        float wy = cy - (float)iy0;
        float wx = cx - (float)ix0;
        // contiguous-pair base with edge-exact weight remap
        int   iya = min(iy0, MSZ - 2);
        int   ixa = min(ix0, MSZ - 2);
        float wya = (iy0 < MSZ - 1) ? wy : 1.0f;
        float wxa = (ix0 < MSZ - 1) ? wx : 1.0f;

        int g0 = (fbm + iya * MSZ + ixa) * 3;     // row iya: 6 contiguous floats
        int g1 = g0 + MSZ * 3;                     // row iya+1

        float va0 = vrt[g0], va1 = vrt[g0+1], va2 = vrt[g0+2];
        float va3 = vrt[g0+3], va4 = vrt[g0+4], va5 = vrt[g0+5];
        float vb0 = vrt[g1], vb1 = vrt[g1+1], vb2 = vrt[g1+2];
        float vb3 = vrt[g1+3], vb4 = vrt[g1+4], vb5 = vrt[g1+5];
        float vx = lerpf(lerpf(va0, va3, wxa), lerpf(vb0, vb3, wxa), wya);
        float vy = lerpf(lerpf(va1, va4, wxa), lerpf(vb1, vb4, wxa), wya);
        float vz = lerpf(lerpf(va2, va5, wxa), lerpf(vb2, vb5, wxa), wya);

        float na0 = nrm[g0], na1 = nrm[g0+1], na2 = nrm[g0+2];
        float na3 = nrm[g0+3], na4 = nrm[g0+4], na5 = nrm[g0+5];
        float nb0 = nrm[g1], nb1 = nrm[g1+1], nb2 = nrm[g1+2];
        float nb3 = nrm[g1+3], nb4 = nrm[g1+4], nb5 = nrm[g1+5];
        float nx = lerpf(lerpf(na0, na3, wxa), lerpf(nb0, nb3, wxa), wya);
        float ny = lerpf(lerpf(na1, na4, wxa), lerpf(nb1, nb4, wxa), wya);
        float nz = lerpf(lerpf(na2, na5, wxa), lerpf(nb2, nb5, wxa), wya);

        float mag = __builtin_amdgcn_sqrtf(nx * nx + ny * ny + nz * nz);
        float sig = fast_sigmoid(ps[fbn + yc * NSZ + xc]);
        float add = 0.5f * sig * mag;
        float ox = vx + add, oy = vy + add, oz = vz + add;

        sv[p * 3 + 0] = ox;
        sv[p * 3 + 1] = oy;
        sv[p * 3 + 2] = oz;
        if (pr >= 1 && pr <= TS && pq >= 1 && pq <= TS) {
            int gi = (fbn + y * NSZ + x) * 3;
            out0[gi + 0] = ox;
            out0[gi + 1] = oy;
            out0[gi + 2] = oz;
        }
    }
    __syncthreads();

    // phase 1.5: unit normals of the 33x33 quad-halo's 2 tris, ONCE, fp16-packed.
    // Out-of-face quads are exactly degenerate (clamped halo duplicates a
    // corner) -> cross = 0 exactly -> packs to 0 -> contributes 0.
    for (int p = threadIdx.x; p < QS * QS; p += 256) {
        int Ri = p / QS, Qi = p - Ri * QS;
        int base = (Ri * HS + Qi) * 3;
        float Axx = sv[base + 0],        Axy = sv[base + 1],        Axz = sv[base + 2];
        float Bxx = sv[base + 3],        Bxy = sv[base + 4],        Bxz = sv[base + 5];
        float Cxx = sv[base + HS*3 + 0], Cxy = sv[base + HS*3 + 1], Cxz = sv[base + HS*3 + 2];
        float Dxx = sv[base + HS*3 + 3], Dxy = sv[base + HS*3 + 4], Dxz = sv[base + HS*3 + 5];

        {   // tri0: (A, B, C)
            float e1x = Bxx - Axx, e1y = Bxy - Axy, e1z = Bxz - Axz;
            float e2x = Cxx - Axx, e2y = Cxy - Axy, e2z = Cxz - Axz;
            float nx = e1y * e2z - e1z * e2y;
            float ny = e1z * e2x - e1x * e2z;
            float nz = e1x * e2y - e1y * e2x;
            float d  = fmaxf(nx * nx + ny * ny + nz * nz, 1e-24f);
            float r  = fast_rsqrt(d);
            tn0p[p] = make_uint2(pkh2(nx * r, ny * r), pkh2(nz * r, 0.0f));
        }
        {   // tri1: (B, D, C)
            float e1x = Dxx - Bxx, e1y = Dxy - Bxy, e1z = Dxz - Bxz;
            float e2x = Cxx - Bxx, e2y = Cxy - Bxy, e2z = Cxz - Bxz;
            float nx = e1y * e2z - e1z * e2y;
            float ny = e1z * e2x - e1x * e2z;
            float nz = e1x * e2y - e1y * e2x;
            float d  = fmaxf(nx * nx + ny * ny + nz * nz, 1e-24f);
            float r  = fast_rsqrt(d);
            tn1p[p] = make_uint2(pkh2(nx * r, ny * r), pkh2(nz * r, 0.0f));
        }
    }
    __syncthreads();

    // phase 2: vertex normal = normalize( sum of 6 adjacent tri normals )
    float sg = (f == 1 || f == 2 || f == 5) ? 1.0f : -1.0f;
    for (int p = threadIdx.x; p < TS * TS; p += 256) {
        int r = p >> 5, q = p & 31;
        int q00 = r * QS + q;
        int q01 = q00 + 1;
        int q10 = q00 + QS;
        int q11 = q10 + 1;

        uint2 u0 = tn0p[q11], u1 = tn0p[q10], u2 = tn0p[q01];
        uint2 u3 = tn1p[q10], u4 = tn1p[q00], u5 = tn1p[q01];

        float2 p0 = uph2(u0.x), p1 = uph2(u1.x), p2 = uph2(u2.x);
        float2 p3 = uph2(u3.x), p4 = uph2(u4.x), p5 = uph2(u5.x);
        float2 z0 = uph2(u0.y), z1 = uph2(u1.y), z2 = uph2(u2.y);
        float2 z3 = uph2(u3.y), z4 = uph2(u4.y), z5 = uph2(u5.y);

        float ax = p0.x + p1.x + p2.x + p3.x + p4.x + p5.x;
        float ay = p0.y + p1.y + p2.y + p3.y + p4.y + p5.y;
        float az = z0.x + z1.x + z2.x + z3.x + z4.x + z5.x;

        float d  = fmaxf(ax * ax + ay * ay + az * az, 1e-24f);
        float rs = fast_rsqrt(d) * sg;
        int gi = (fbn + (tr + r) * NSZ + (tq + q)) * 3;
        out2[gi + 0] = ax * rs;
        out2[gi + 1] = ay * rs;
        out2[gi + 2] = az * rs;
    }
}

extern "C" void kernel_launch(void* const* d_in, const int* in_sizes, int n_in,
                              void* d_out, int out_size, void* d_ws, size_t ws_size,
                              hipStream_t stream) {
    const float* vrt = (const float*)d_in[0];
    const float* nrm = (const float*)d_in[1];
    const float* ps  = (const float*)d_in[2];

    float* out0 = (float*)d_out;                 // vert:    6*512*512*3
    float* out1 = out0 + (size_t)NPIX * 3;       // faces:   NFACE*3
    float* out2 = out1 + (size_t)F3TOT;          // normals: 6*512*512*3

    k_all<<<GRID, 256, 0, stream>>>(vrt, nrm, ps, out0, out1, out2);
}